// Round 7
// baseline (27.421 us; speedup 1.0000x reference)
//
#include <hip/hip_runtime.h>
#include <hip/hip_fp16.h>
#include <math.h>

#define NPOS 16384
#define NTOT 491520
#define NFEAT 768
#define DUMMY 768          // zero row appended to W1T
#define PITCH 68           // halves per W1T row: 136B -> 8B-aligned, bank-friendly

typedef _Float16 h2 __attribute__((ext_vector_type(2)));

__device__ __forceinline__ int imin(int a, int b) { return a < b ? a : b; }
__device__ __forceinline__ float clamp01(float x) { return fminf(fmaxf(x, 0.f), 1.f); }

#if __has_builtin(__builtin_amdgcn_fdot2)
#define FDOT2(a, b, c) __builtin_amdgcn_fdot2((a), (b), (c), false)
#else
#define FDOT2(a, b, c) ((c) + (float)(a)[0] * (float)(b)[0] + (float)(a)[1] * (float)(b)[1])
#endif

__device__ __forceinline__ h2 toh2(__half2 x) { return __builtin_bit_cast(h2, x); }

// ---------------- single fused kernel ----------------
// 256 blocks (1/CU) x 1024 threads (16 waves), ~121.5KB LDS -> 1 block/CU.
// Phase A: waves 0-13 stage W1 -> LDS fp16 [769][PITCH] (transposed).
//          waves 14/15: 65 white/black segment boundaries via INTERPOLATION
//          search (~4-5 dependent probes vs 19 for binary), then W2->LDS.
// Phase B: wave w handles positions p0 + w + 16*it, it=0..3:
//          per 16-row chunk: 1 broadcast ds_read_b128 (index quad per 16-lane
//          group) + 4 ds_read_b64 row reads + f32 accumulate (passes accuracy;
//          fp16 packed accum FAILED in R6 at 1.95e-2 > 1.02e-2).
//          Then xor-reduce, bias+hardtanh+pack to LDS, head with W2T in VGPRs.
__global__ __launch_bounds__(1024, 4) void k_all(
    const int* __restrict__ wf, const int* __restrict__ bf,
    const int* __restrict__ wi, const int* __restrict__ bi,
    const float* __restrict__ W1, const float4* __restrict__ b1q,
    const float* __restrict__ W2, const float* __restrict__ b2,
    const float* __restrict__ W3, const float* __restrict__ b3,
    float* __restrict__ out)
{
    __shared__ __half  w1t[769 * PITCH];           // 104,584 B
    __shared__ __half2 w2t[2048];                  // [i-pair 0..63][j 0..31]
    __shared__ __align__(16) int ivs[16][64];      // per-wave index window
    __shared__ uint4   a1sq[16][16];               // per-wave a1 row (128 halfs)
    __shared__ int     sb[2][65];                  // segment boundaries

    int t = threadIdx.x;
    int wave = t >> 6, lane = t & 63;
    int p0 = blockIdx.x * 64;

    // ---- Phase A ----
    if (wave < 14) {
        // W1 [64][768] f32 -> w1t[f][r] fp16. f4 = float4 column group (f4%14==wave).
        int r = lane;
        const float* wrow = W1 + r * NFEAT;
#pragma unroll 2
        for (int i = 0; i < 14; ++i) {
            int f4 = wave + 14 * i;
            if (f4 >= 192) break;
            float4 v = *(const float4*)&wrow[f4 * 4];
            int fb = f4 * 4;
            w1t[(fb + 0) * PITCH + r] = __float2half(v.x);
            w1t[(fb + 1) * PITCH + r] = __float2half(v.y);
            w1t[(fb + 2) * PITCH + r] = __float2half(v.z);
            w1t[(fb + 3) * PITCH + r] = __float2half(v.w);
        }
    } else {
        // Dual interpolation lower_bound: lane l -> tgt1 = p0+l; all lanes also
        // run the tgt2 = p0+64 chain interleaved (same wall latency), lane 63 stores.
        const int* __restrict__ arr = (wave == 14) ? wi : bi;
        int col = wave - 14;
        int t1 = p0 + lane, t2 = p0 + 64;
        int lo1 = 0, hi1 = 0, g1 = 0;
        int lo2 = 0, hi2 = 0, g2 = 0;
        if (t1 > 0) { hi1 = NTOT; g1 = imin(t1 * 30, NTOT - 1); }
        if (t2 < NPOS) { hi2 = NTOT; g2 = imin(t2 * 30, NTOT - 1); }
        else { lo2 = NTOT; hi2 = NTOT; }
#pragma unroll 1
        for (int it = 0; it < 8; ++it) {
            bool c1 = lo1 < hi1, c2 = lo2 < hi2;
            if (!c1 && !c2) break;
            int v1 = 0, v2 = 0;
            if (c1) v1 = arr[g1];                 // both probes in flight together
            if (c2) v2 = arr[g2];
            if (c1) {
                if (v1 < t1) lo1 = g1 + 1; else hi1 = g1;
                int ng = g1 + (t1 - v1) * 30;     // interpolation step
                if (ng < lo1 || ng >= hi1) ng = lo1 + ((hi1 - lo1) >> 1);
                g1 = ng;
            }
            if (c2) {
                if (v2 < t2) lo2 = g2 + 1; else hi2 = g2;
                int ng = g2 + (t2 - v2) * 30;
                if (ng < lo2 || ng >= hi2) ng = lo2 + ((hi2 - lo2) >> 1);
                g2 = ng;
            }
        }
#pragma unroll 1
        for (;;) {                                // binary finish (tiny brackets)
            bool c1 = lo1 < hi1, c2 = lo2 < hi2;
            if (!c1 && !c2) break;
            int m1 = 0, m2 = 0, v1 = 0, v2 = 0;
            if (c1) { m1 = lo1 + ((hi1 - lo1) >> 1); v1 = arr[m1]; }
            if (c2) { m2 = lo2 + ((hi2 - lo2) >> 1); v2 = arr[m2]; }
            if (c1) { if (v1 < t1) lo1 = m1 + 1; else hi1 = m1; }
            if (c2) { if (v2 < t2) lo2 = m2 + 1; else hi2 = m2; }
        }
        sb[col][lane] = lo1;
        if (lane == 63) sb[col][64] = lo2;

        // W2 [32][128] f32 -> w2t[i*32+j] = (W2[j][2i], W2[j][2i+1]); threads 896..1023
        int tl = t - 896;
        for (int x = tl; x < 2048; x += 128) {
            int i = x >> 5, jj = x & 31;
            w2t[x] = __floats2half2_rn(W2[jj * 128 + 2 * i], W2[jj * 128 + 2 * i + 1]);
        }
        if (tl < 64) w1t[DUMMY * PITCH + tl] = __float2half(0.f);
    }
    __syncthreads();

    // ---- Phase B ----
    int g = lane >> 4, k = lane & 15;
    int j = lane & 31, h = lane >> 5;

    // W2T slice for this lane's (j,h) into 32 VGPRs, reused for all 4 positions
    h2 w2r[32];
#pragma unroll
    for (int i = 0; i < 32; ++i) w2r[i] = toh2(w2t[(h * 32 + i) * 32 + j]);

    float4 bb = b1q[k];
    float b2j = b2[j], w3j = W3[j], b30 = b3[0];

    int* myiv = &ivs[wave][0];
    __half2* a1h = (__half2*)&a1sq[wave][0];

    for (int it = 0; it < 4; ++it) {
        int pl = wave + 16 * it;              // local position 0..63
        int pos = p0 + pl;
        int ws_ = sb[0][pl], we = sb[0][pl + 1];
        int bs_ = sb[1][pl], be = sb[1][pl + 1];

        float wa0 = 0.f, wa1 = 0.f, wa2 = 0.f, wa3 = 0.f;
        float ba0 = 0.f, ba1 = 0.f, ba2 = 0.f, ba3 = 0.f;

        auto run = [&](const int* __restrict__ feats, int s, int e,
                       float& A0, float& A1, float& A2, float& A3) {
            for (int tt = s; tt < e; tt += 64) {
                myiv[lane] = (tt + lane < e) ? feats[tt + lane] : DUMMY;
                int nc = (imin(e - tt, 64) + 15) >> 4;    // 16-row chunks
                for (int c = 0; c < nc; ++c) {
                    // broadcast quad of row indices: group g takes rows c*16+g*4..+3
                    uint4 iq = *(const uint4*)&myiv[c * 16 + g * 4];
                    uint2 d0 = *(const uint2*)&w1t[(int)iq.x * PITCH + k * 4];
                    uint2 d1 = *(const uint2*)&w1t[(int)iq.y * PITCH + k * 4];
                    uint2 d2 = *(const uint2*)&w1t[(int)iq.z * PITCH + k * 4];
                    uint2 d3 = *(const uint2*)&w1t[(int)iq.w * PITCH + k * 4];
                    h2 l0 = __builtin_bit_cast(h2, d0.x), u0 = __builtin_bit_cast(h2, d0.y);
                    h2 l1 = __builtin_bit_cast(h2, d1.x), u1 = __builtin_bit_cast(h2, d1.y);
                    h2 l2 = __builtin_bit_cast(h2, d2.x), u2 = __builtin_bit_cast(h2, d2.y);
                    h2 l3 = __builtin_bit_cast(h2, d3.x), u3 = __builtin_bit_cast(h2, d3.y);
                    A0 += (float)l0[0] + (float)l1[0] + (float)l2[0] + (float)l3[0];
                    A1 += (float)l0[1] + (float)l1[1] + (float)l2[1] + (float)l3[1];
                    A2 += (float)u0[0] + (float)u1[0] + (float)u2[0] + (float)u3[0];
                    A3 += (float)u0[1] + (float)u1[1] + (float)u2[1] + (float)u3[1];
                }
            }
        };
        run(wf, ws_, we, wa0, wa1, wa2, wa3);
        run(bf, bs_, be, ba0, ba1, ba2, ba3);

        wa0 += __shfl_xor(wa0, 16); wa0 += __shfl_xor(wa0, 32);
        wa1 += __shfl_xor(wa1, 16); wa1 += __shfl_xor(wa1, 32);
        wa2 += __shfl_xor(wa2, 16); wa2 += __shfl_xor(wa2, 32);
        wa3 += __shfl_xor(wa3, 16); wa3 += __shfl_xor(wa3, 32);
        ba0 += __shfl_xor(ba0, 16); ba0 += __shfl_xor(ba0, 32);
        ba1 += __shfl_xor(ba1, 16); ba1 += __shfl_xor(ba1, 32);
        ba2 += __shfl_xor(ba2, 16); ba2 += __shfl_xor(ba2, 32);
        ba3 += __shfl_xor(ba3, 16); ba3 += __shfl_xor(ba3, 32);

        if (lane < 32) {
            __half2 q0, q1;
            if (g == 0) {
                q0 = __floats2half2_rn(clamp01(wa0 + bb.x), clamp01(wa1 + bb.y));
                q1 = __floats2half2_rn(clamp01(wa2 + bb.z), clamp01(wa3 + bb.w));
            } else {
                q0 = __floats2half2_rn(clamp01(ba0 + bb.x), clamp01(ba1 + bb.y));
                q1 = __floats2half2_rn(clamp01(ba2 + bb.z), clamp01(ba3 + bb.w));
            }
            a1h[g * 32 + k * 2]     = q0;     // white pairs in [0..31], black [32..63]
            a1h[g * 32 + k * 2 + 1] = q1;
        }
        // same-wave LDS write->read: compiler-inserted lgkmcnt ordering

        // head: lane (j,h): dot of half h (32 half2, b128 broadcast reads) with w2r
        const uint4* aq = &a1sq[wave][h * 8];
        float acc = 0.f;
#pragma unroll
        for (int q4 = 0; q4 < 8; ++q4) {
            uint4 qq = aq[q4];
            acc = FDOT2(__builtin_bit_cast(h2, qq.x), w2r[q4 * 4 + 0], acc);
            acc = FDOT2(__builtin_bit_cast(h2, qq.y), w2r[q4 * 4 + 1], acc);
            acc = FDOT2(__builtin_bit_cast(h2, qq.z), w2r[q4 * 4 + 2], acc);
            acc = FDOT2(__builtin_bit_cast(h2, qq.w), w2r[q4 * 4 + 3], acc);
        }
        acc += __shfl_xor(acc, 32);

        float a2v = clamp01(acc + b2j);
        float p = a2v * w3j;
        p += __shfl_xor(p, 16);
        p += __shfl_xor(p, 8);
        p += __shfl_xor(p, 4);
        p += __shfl_xor(p, 2);
        p += __shfl_xor(p, 1);
        if (lane == 0)
            out[pos] = 1.f / (1.f + __expf(-(p + b30)));
    }
}

extern "C" void kernel_launch(void* const* d_in, const int* in_sizes, int n_in,
                              void* d_out, int out_size, void* d_ws, size_t ws_size,
                              hipStream_t stream) {
    const int*   wf = (const int*)d_in[0];
    const int*   wi = (const int*)d_in[1];
    const int*   bf = (const int*)d_in[2];
    const int*   bi = (const int*)d_in[3];
    const float* W1 = (const float*)d_in[4];
    const float* b1 = (const float*)d_in[5];
    const float* W2 = (const float*)d_in[6];
    const float* b2 = (const float*)d_in[7];
    const float* W3 = (const float*)d_in[8];
    const float* b3 = (const float*)d_in[9];
    float* out = (float*)d_out;

    k_all<<<NPOS / 64, 1024, 0, stream>>>(wf, bf, wi, bi, W1, (const float4*)b1,
                                          W2, b2, W3, b3, out);
}

// Round 8
// 26.455 us; speedup vs baseline: 1.0365x; 1.0365x over previous
//
#include <hip/hip_runtime.h>
#include <hip/hip_fp16.h>
#include <math.h>

#define NPOS 16384
#define NTOT 491520
#define NFEAT 768
#define DUMMY 768          // zero row appended to W1T
#define PITCH 68           // halves per W1T row: 136B -> 8B-aligned, bank-friendly

typedef _Float16 h2 __attribute__((ext_vector_type(2)));

__device__ __forceinline__ int imin(int a, int b) { return a < b ? a : b; }
__device__ __forceinline__ float clamp01(float x) { return fminf(fmaxf(x, 0.f), 1.f); }

#if __has_builtin(__builtin_amdgcn_fdot2)
#define FDOT2(a, b, c) __builtin_amdgcn_fdot2((a), (b), (c), false)
#else
#define FDOT2(a, b, c) ((c) + (float)(a)[0] * (float)(b)[0] + (float)(a)[1] * (float)(b)[1])
#endif

// pack (lo16(x), lo16(y)) and (hi16(x), hi16(y)) into uint32s
#if __has_builtin(__builtin_amdgcn_perm)
#define PACK_LO(x, y) __builtin_amdgcn_perm((y), (x), 0x05040100u)
#define PACK_HI(x, y) __builtin_amdgcn_perm((y), (x), 0x07060302u)
#else
#define PACK_LO(x, y) (((x) & 0xFFFFu) | ((y) << 16))
#define PACK_HI(x, y) (((x) >> 16) | ((y) & 0xFFFF0000u))
#endif

__device__ __forceinline__ h2 toh2(__half2 x) { return __builtin_bit_cast(h2, x); }

// ---------------- single fused kernel ----------------
// 256 blocks (1/CU) x 1024 threads (16 waves), ~126KB LDS -> 1 block/CU.
// Phase A: waves 0-13 stage W1 -> LDS fp16 [769][PITCH] (transposed);
//          waves 14/15: interpolation-search the 65 white/black segment
//          boundaries; W2 -> LDS. One barrier.
// Phase B: wave w owns positions p0 + w + 16*it. Per position:
//          white+black index windows prefetched one iteration ahead (regs),
//          both colors' 16-row chunks interleaved (2 LDS dep-chains in
//          flight); chunk body = 1 ds_read_b128 (index quad) + 4 ds_read_b64
//          (rows) + 8 v_perm + 8 v_dot2_f32_f16 with (1,1) -- f32 accumulate
//          (fp16 accum FAILED accuracy in R6; perm+fdot2 keeps f32 exact).
//          Then xor-reduce, bias+hardtanh+pack to LDS, head with W2T in VGPRs.
__global__ __launch_bounds__(1024, 4) void k_all(
    const int* __restrict__ wf, const int* __restrict__ bf,
    const int* __restrict__ wi, const int* __restrict__ bi,
    const float* __restrict__ W1, const float4* __restrict__ b1q,
    const float* __restrict__ W2, const float* __restrict__ b2,
    const float* __restrict__ W3, const float* __restrict__ b3,
    float* __restrict__ out)
{
    __shared__ __half  w1t[769 * PITCH];           // 104,584 B
    __shared__ __half2 w2t[2048];                  // [i-pair 0..63][j 0..31]
    __shared__ __align__(16) int ivs[16][2][64];   // per-wave windows (w/b)
    __shared__ uint4   a1sq[16][16];               // per-wave a1 row (128 halfs)
    __shared__ int     sb[2][65];                  // segment boundaries

    int t = threadIdx.x;
    int wave = t >> 6, lane = t & 63;
    int p0 = blockIdx.x * 64;

    // ---- Phase A ----
    if (wave < 14) {
        int r = lane;
        const float* wrow = W1 + r * NFEAT;
#pragma unroll 2
        for (int i = 0; i < 14; ++i) {
            int f4 = wave + 14 * i;
            if (f4 >= 192) break;
            float4 v = *(const float4*)&wrow[f4 * 4];
            int fb = f4 * 4;
            w1t[(fb + 0) * PITCH + r] = __float2half(v.x);
            w1t[(fb + 1) * PITCH + r] = __float2half(v.y);
            w1t[(fb + 2) * PITCH + r] = __float2half(v.z);
            w1t[(fb + 3) * PITCH + r] = __float2half(v.w);
        }
    } else {
        // Dual interpolation lower_bound per lane (tgt1 = p0+lane, tgt2 = p0+64)
        const int* __restrict__ arr = (wave == 14) ? wi : bi;
        int col = wave - 14;
        int t1 = p0 + lane, t2 = p0 + 64;
        int lo1 = 0, hi1 = 0, g1 = 0;
        int lo2 = 0, hi2 = 0, g2 = 0;
        if (t1 > 0) { hi1 = NTOT; g1 = imin(t1 * 30, NTOT - 1); }
        if (t2 < NPOS) { hi2 = NTOT; g2 = imin(t2 * 30, NTOT - 1); }
        else { lo2 = NTOT; hi2 = NTOT; }
#pragma unroll 1
        for (int it = 0; it < 8; ++it) {
            bool c1 = lo1 < hi1, c2 = lo2 < hi2;
            if (!c1 && !c2) break;
            int v1 = 0, v2 = 0;
            if (c1) v1 = arr[g1];
            if (c2) v2 = arr[g2];
            if (c1) {
                if (v1 < t1) lo1 = g1 + 1; else hi1 = g1;
                int ng = g1 + (t1 - v1) * 30;
                if (ng < lo1 || ng >= hi1) ng = lo1 + ((hi1 - lo1) >> 1);
                g1 = ng;
            }
            if (c2) {
                if (v2 < t2) lo2 = g2 + 1; else hi2 = g2;
                int ng = g2 + (t2 - v2) * 30;
                if (ng < lo2 || ng >= hi2) ng = lo2 + ((hi2 - lo2) >> 1);
                g2 = ng;
            }
        }
#pragma unroll 1
        for (;;) {
            bool c1 = lo1 < hi1, c2 = lo2 < hi2;
            if (!c1 && !c2) break;
            int m1 = 0, m2 = 0, v1 = 0, v2 = 0;
            if (c1) { m1 = lo1 + ((hi1 - lo1) >> 1); v1 = arr[m1]; }
            if (c2) { m2 = lo2 + ((hi2 - lo2) >> 1); v2 = arr[m2]; }
            if (c1) { if (v1 < t1) lo1 = m1 + 1; else hi1 = m1; }
            if (c2) { if (v2 < t2) lo2 = m2 + 1; else hi2 = m2; }
        }
        sb[col][lane] = lo1;
        if (lane == 63) sb[col][64] = lo2;

        int tl = t - 896;
        for (int x = tl; x < 2048; x += 128) {
            int i = x >> 5, jj = x & 31;
            w2t[x] = __floats2half2_rn(W2[jj * 128 + 2 * i], W2[jj * 128 + 2 * i + 1]);
        }
        if (tl < 64) w1t[DUMMY * PITCH + tl] = __float2half(0.f);
    }
    __syncthreads();

    // ---- Phase B ----
    int g = lane >> 4, k = lane & 15;
    int j = lane & 31, h = lane >> 5;

    // first position's bounds + window prefetch (flies during w2r preload)
    int ws_ = sb[0][wave], we = sb[0][wave + 1];
    int bs_ = sb[1][wave], be = sb[1][wave + 1];
    int nivw = (ws_ + lane < we) ? wf[ws_ + lane] : DUMMY;
    int nivb = (bs_ + lane < be) ? bf[bs_ + lane] : DUMMY;

    // W2T slice for this lane's (j,h) into 32 VGPRs
    h2 w2r[32];
#pragma unroll
    for (int i = 0; i < 32; ++i) w2r[i] = toh2(w2t[(h * 32 + i) * 32 + j]);

    float4 bb = b1q[k];
    float b2j = b2[j], w3j = W3[j], b30 = b3[0];

    const h2 ones = {(_Float16)1.0f, (_Float16)1.0f};
    int* ivW = &ivs[wave][0][0];
    int* ivB = &ivs[wave][1][0];
    __half2* a1h = (__half2*)&a1sq[wave][0];

    // chunk: 4 rows (indices miv[c*16+g*4 ..+3]), perm-pair + fdot2, f32 accum
    auto CHUNK = [&](const int* __restrict__ miv, int c,
                     float& A0, float& A1, float& A2, float& A3) {
        uint4 iq = *(const uint4*)&miv[c * 16 + g * 4];
        uint2 d0 = *(const uint2*)&w1t[(int)iq.x * PITCH + k * 4];
        uint2 d1 = *(const uint2*)&w1t[(int)iq.y * PITCH + k * 4];
        uint2 d2 = *(const uint2*)&w1t[(int)iq.z * PITCH + k * 4];
        uint2 d3 = *(const uint2*)&w1t[(int)iq.w * PITCH + k * 4];
        A0 = FDOT2(__builtin_bit_cast(h2, PACK_LO(d0.x, d1.x)), ones, A0);
        A1 = FDOT2(__builtin_bit_cast(h2, PACK_HI(d0.x, d1.x)), ones, A1);
        A2 = FDOT2(__builtin_bit_cast(h2, PACK_LO(d0.y, d1.y)), ones, A2);
        A3 = FDOT2(__builtin_bit_cast(h2, PACK_HI(d0.y, d1.y)), ones, A3);
        A0 = FDOT2(__builtin_bit_cast(h2, PACK_LO(d2.x, d3.x)), ones, A0);
        A1 = FDOT2(__builtin_bit_cast(h2, PACK_HI(d2.x, d3.x)), ones, A1);
        A2 = FDOT2(__builtin_bit_cast(h2, PACK_LO(d2.y, d3.y)), ones, A2);
        A3 = FDOT2(__builtin_bit_cast(h2, PACK_HI(d2.y, d3.y)), ones, A3);
    };

    for (int it = 0; it < 4; ++it) {
        int pl = wave + 16 * it;
        int pos = p0 + pl;

        // stage this position's windows (same-wave LDS: in-order, no barrier)
        ivW[lane] = nivw;
        ivB[lane] = nivb;
        int cws = ws_, cwe = we, cbs = bs_, cbe = be;

        // prefetch next position's bounds + windows
        if (it < 3) {
            int npl = pl + 16;
            ws_ = sb[0][npl]; we = sb[0][npl + 1];
            bs_ = sb[1][npl]; be = sb[1][npl + 1];
            nivw = (ws_ + lane < we) ? wf[ws_ + lane] : DUMMY;
            nivb = (bs_ + lane < be) ? bf[bs_ + lane] : DUMMY;
        }

        float wa0 = 0.f, wa1 = 0.f, wa2 = 0.f, wa3 = 0.f;
        float ba0 = 0.f, ba1 = 0.f, ba2 = 0.f, ba3 = 0.f;

        // interleaved white/black chunks: 2 LDS dep-chains in flight
        int ncw = (imin(cwe - cws, 64) + 15) >> 4;
        int ncb = (imin(cbe - cbs, 64) + 15) >> 4;
        int ncm = ncw > ncb ? ncw : ncb;
        for (int c = 0; c < ncm; ++c) {
            if (c < ncw) CHUNK(ivW, c, wa0, wa1, wa2, wa3);
            if (c < ncb) CHUNK(ivB, c, ba0, ba1, ba2, ba3);
        }
        // rare tails (segment > 64 rows)
        for (int tt = cws + 64; tt < cwe; tt += 64) {
            ivW[lane] = (tt + lane < cwe) ? wf[tt + lane] : DUMMY;
            int nc = (imin(cwe - tt, 64) + 15) >> 4;
            for (int c = 0; c < nc; ++c) CHUNK(ivW, c, wa0, wa1, wa2, wa3);
        }
        for (int tt = cbs + 64; tt < cbe; tt += 64) {
            ivB[lane] = (tt + lane < cbe) ? bf[tt + lane] : DUMMY;
            int nc = (imin(cbe - tt, 64) + 15) >> 4;
            for (int c = 0; c < nc; ++c) CHUNK(ivB, c, ba0, ba1, ba2, ba3);
        }

        wa0 += __shfl_xor(wa0, 16); wa0 += __shfl_xor(wa0, 32);
        wa1 += __shfl_xor(wa1, 16); wa1 += __shfl_xor(wa1, 32);
        wa2 += __shfl_xor(wa2, 16); wa2 += __shfl_xor(wa2, 32);
        wa3 += __shfl_xor(wa3, 16); wa3 += __shfl_xor(wa3, 32);
        ba0 += __shfl_xor(ba0, 16); ba0 += __shfl_xor(ba0, 32);
        ba1 += __shfl_xor(ba1, 16); ba1 += __shfl_xor(ba1, 32);
        ba2 += __shfl_xor(ba2, 16); ba2 += __shfl_xor(ba2, 32);
        ba3 += __shfl_xor(ba3, 16); ba3 += __shfl_xor(ba3, 32);

        if (lane < 32) {
            __half2 q0, q1;
            if (g == 0) {
                q0 = __floats2half2_rn(clamp01(wa0 + bb.x), clamp01(wa1 + bb.y));
                q1 = __floats2half2_rn(clamp01(wa2 + bb.z), clamp01(wa3 + bb.w));
            } else {
                q0 = __floats2half2_rn(clamp01(ba0 + bb.x), clamp01(ba1 + bb.y));
                q1 = __floats2half2_rn(clamp01(ba2 + bb.z), clamp01(ba3 + bb.w));
            }
            a1h[g * 32 + k * 2]     = q0;     // white pairs [0..31], black [32..63]
            a1h[g * 32 + k * 2 + 1] = q1;
        }
        // same-wave LDS write->read ordering via lgkmcnt

        const uint4* aq = &a1sq[wave][h * 8];
        float acc = 0.f;
#pragma unroll
        for (int q4 = 0; q4 < 8; ++q4) {
            uint4 qq = aq[q4];
            acc = FDOT2(__builtin_bit_cast(h2, qq.x), w2r[q4 * 4 + 0], acc);
            acc = FDOT2(__builtin_bit_cast(h2, qq.y), w2r[q4 * 4 + 1], acc);
            acc = FDOT2(__builtin_bit_cast(h2, qq.z), w2r[q4 * 4 + 2], acc);
            acc = FDOT2(__builtin_bit_cast(h2, qq.w), w2r[q4 * 4 + 3], acc);
        }
        acc += __shfl_xor(acc, 32);

        float a2v = clamp01(acc + b2j);
        float p = a2v * w3j;
        p += __shfl_xor(p, 16);
        p += __shfl_xor(p, 8);
        p += __shfl_xor(p, 4);
        p += __shfl_xor(p, 2);
        p += __shfl_xor(p, 1);
        if (lane == 0)
            out[pos] = 1.f / (1.f + __expf(-(p + b30)));
    }
}

extern "C" void kernel_launch(void* const* d_in, const int* in_sizes, int n_in,
                              void* d_out, int out_size, void* d_ws, size_t ws_size,
                              hipStream_t stream) {
    const int*   wf = (const int*)d_in[0];
    const int*   wi = (const int*)d_in[1];
    const int*   bf = (const int*)d_in[2];
    const int*   bi = (const int*)d_in[3];
    const float* W1 = (const float*)d_in[4];
    const float* b1 = (const float*)d_in[5];
    const float* W2 = (const float*)d_in[6];
    const float* b2 = (const float*)d_in[7];
    const float* W3 = (const float*)d_in[8];
    const float* b3 = (const float*)d_in[9];
    float* out = (float*)d_out;

    k_all<<<NPOS / 64, 1024, 0, stream>>>(wf, bf, wi, bi, W1, (const float4*)b1,
                                          W2, b2, W3, b3, out);
}

// Round 9
// 24.907 us; speedup vs baseline: 1.1009x; 1.0621x over previous
//
#include <hip/hip_runtime.h>
#include <hip/hip_fp16.h>
#include <math.h>

#define NPOS 16384
#define NTOT 491520
#define NFEAT 768
#define DUMMY 768          // zero row appended to W1T
#define PITCH 68           // halves per W1T row: 136B -> 8B-aligned, bank-friendly

typedef _Float16 h2 __attribute__((ext_vector_type(2)));

__device__ __forceinline__ int imin(int a, int b) { return a < b ? a : b; }
__device__ __forceinline__ float clamp01(float x) { return fminf(fmaxf(x, 0.f), 1.f); }

#if __has_builtin(__builtin_amdgcn_fdot2)
#define FDOT2(a, b, c) __builtin_amdgcn_fdot2((a), (b), (c), false)
#else
#define FDOT2(a, b, c) ((c) + (float)(a)[0] * (float)(b)[0] + (float)(a)[1] * (float)(b)[1])
#endif

// pack (lo16(x), lo16(y)) and (hi16(x), hi16(y)) into uint32s
#if __has_builtin(__builtin_amdgcn_perm)
#define PACK_LO(x, y) __builtin_amdgcn_perm((y), (x), 0x05040100u)
#define PACK_HI(x, y) __builtin_amdgcn_perm((y), (x), 0x07060302u)
#else
#define PACK_LO(x, y) (((x) & 0xFFFFu) | ((y) << 16))
#define PACK_HI(x, y) (((x) >> 16) | ((y) & 0xFFFF0000u))
#endif

__device__ __forceinline__ h2 toh2(__half2 x) { return __builtin_bit_cast(h2, x); }

// ---------------- single fused kernel ----------------
// 256 blocks (1/CU) x 1024 threads (16 waves), ~126KB LDS -> 1 block/CU.
// Phase A (FIXED in R9): waves 0-13 stage W1 -> LDS with COALESCED reads:
//   work item (r, s) -> lane reads W1[r*768 + s*64 + lane] (256B contiguous
//   per wave-instruction; R8's layout had lane stride 3072B = 64 cache lines
//   per load, ~4x overfetch, ~6us before the barrier). LDS write at
//   (s*64+lane)*PITCH + r: lane dword-stride 34 -> 2 lanes/bank = free.
//   Waves 14/15: interpolation search for segment boundaries + W2 -> LDS.
// Phase B (unchanged from R8, passed at 1.95e-3): per position, interleaved
//   white/black 16-row chunks: ds_read_b128 index quad + 4 ds_read_b64 rows +
//   8 v_perm + 8 v_dot2_f32_f16((1,1)) f32 accumulate; xor-reduce;
//   bias+hardtanh+pack to LDS; head with W2T in VGPRs.
__global__ __launch_bounds__(1024, 4) void k_all(
    const int* __restrict__ wf, const int* __restrict__ bf,
    const int* __restrict__ wi, const int* __restrict__ bi,
    const float* __restrict__ W1, const float4* __restrict__ b1q,
    const float* __restrict__ W2, const float* __restrict__ b2,
    const float* __restrict__ W3, const float* __restrict__ b3,
    float* __restrict__ out)
{
    __shared__ __half  w1t[769 * PITCH];           // 104,584 B
    __shared__ __half2 w2t[2048];                  // [i-pair 0..63][j 0..31]
    __shared__ __align__(16) int ivs[16][2][64];   // per-wave windows (w/b)
    __shared__ uint4   a1sq[16][16];               // per-wave a1 row (128 halfs)
    __shared__ int     sb[2][65];                  // segment boundaries

    int t = threadIdx.x;
    int wave = t >> 6, lane = t & 63;
    int p0 = blockIdx.x * 64;

    // ---- Phase A ----
    if (wave < 14) {
        // 768 work items (r = W1 row 0..63, s = 64-col span 0..11), wave-strided.
        // item = r*12 + s; lane supplies the column within the span.
#pragma unroll 4
        for (int i = 0; i < 55; ++i) {
            int item = wave + 14 * i;
            if (item >= 768) break;
            int r = item / 12;              // wave-uniform -> SALU magic-mul
            int s = item - r * 12;
            float v = W1[r * NFEAT + s * 64 + lane];   // 256B coalesced
            w1t[(s * 64 + lane) * PITCH + r] = __float2half(v);
        }
    } else {
        // Dual interpolation lower_bound per lane (tgt1 = p0+lane, tgt2 = p0+64)
        const int* __restrict__ arr = (wave == 14) ? wi : bi;
        int col = wave - 14;
        int t1 = p0 + lane, t2 = p0 + 64;
        int lo1 = 0, hi1 = 0, g1 = 0;
        int lo2 = 0, hi2 = 0, g2 = 0;
        if (t1 > 0) { hi1 = NTOT; g1 = imin(t1 * 30, NTOT - 1); }
        if (t2 < NPOS) { hi2 = NTOT; g2 = imin(t2 * 30, NTOT - 1); }
        else { lo2 = NTOT; hi2 = NTOT; }
#pragma unroll 1
        for (int it = 0; it < 8; ++it) {
            bool c1 = lo1 < hi1, c2 = lo2 < hi2;
            if (!c1 && !c2) break;
            int v1 = 0, v2 = 0;
            if (c1) v1 = arr[g1];
            if (c2) v2 = arr[g2];
            if (c1) {
                if (v1 < t1) lo1 = g1 + 1; else hi1 = g1;
                int ng = g1 + (t1 - v1) * 30;
                if (ng < lo1 || ng >= hi1) ng = lo1 + ((hi1 - lo1) >> 1);
                g1 = ng;
            }
            if (c2) {
                if (v2 < t2) lo2 = g2 + 1; else hi2 = g2;
                int ng = g2 + (t2 - v2) * 30;
                if (ng < lo2 || ng >= hi2) ng = lo2 + ((hi2 - lo2) >> 1);
                g2 = ng;
            }
        }
#pragma unroll 1
        for (;;) {
            bool c1 = lo1 < hi1, c2 = lo2 < hi2;
            if (!c1 && !c2) break;
            int m1 = 0, m2 = 0, v1 = 0, v2 = 0;
            if (c1) { m1 = lo1 + ((hi1 - lo1) >> 1); v1 = arr[m1]; }
            if (c2) { m2 = lo2 + ((hi2 - lo2) >> 1); v2 = arr[m2]; }
            if (c1) { if (v1 < t1) lo1 = m1 + 1; else hi1 = m1; }
            if (c2) { if (v2 < t2) lo2 = m2 + 1; else hi2 = m2; }
        }
        sb[col][lane] = lo1;
        if (lane == 63) sb[col][64] = lo2;

        int tl = t - 896;
        for (int x = tl; x < 2048; x += 128) {
            int i = x >> 5, jj = x & 31;
            w2t[x] = __floats2half2_rn(W2[jj * 128 + 2 * i], W2[jj * 128 + 2 * i + 1]);
        }
        if (tl < 64) w1t[DUMMY * PITCH + tl] = __float2half(0.f);
    }
    __syncthreads();

    // ---- Phase B ----
    int g = lane >> 4, k = lane & 15;
    int j = lane & 31, h = lane >> 5;

    // first position's bounds + window prefetch (flies during w2r preload)
    int ws_ = sb[0][wave], we = sb[0][wave + 1];
    int bs_ = sb[1][wave], be = sb[1][wave + 1];
    int nivw = (ws_ + lane < we) ? wf[ws_ + lane] : DUMMY;
    int nivb = (bs_ + lane < be) ? bf[bs_ + lane] : DUMMY;

    // W2T slice for this lane's (j,h) into 32 VGPRs
    h2 w2r[32];
#pragma unroll
    for (int i = 0; i < 32; ++i) w2r[i] = toh2(w2t[(h * 32 + i) * 32 + j]);

    float4 bb = b1q[k];
    float b2j = b2[j], w3j = W3[j], b30 = b3[0];

    const h2 ones = {(_Float16)1.0f, (_Float16)1.0f};
    int* ivW = &ivs[wave][0][0];
    int* ivB = &ivs[wave][1][0];
    __half2* a1h = (__half2*)&a1sq[wave][0];

    // chunk: 4 rows (indices miv[c*16+g*4 ..+3]), perm-pair + fdot2, f32 accum
    auto CHUNK = [&](const int* __restrict__ miv, int c,
                     float& A0, float& A1, float& A2, float& A3) {
        uint4 iq = *(const uint4*)&miv[c * 16 + g * 4];
        uint2 d0 = *(const uint2*)&w1t[(int)iq.x * PITCH + k * 4];
        uint2 d1 = *(const uint2*)&w1t[(int)iq.y * PITCH + k * 4];
        uint2 d2 = *(const uint2*)&w1t[(int)iq.z * PITCH + k * 4];
        uint2 d3 = *(const uint2*)&w1t[(int)iq.w * PITCH + k * 4];
        A0 = FDOT2(__builtin_bit_cast(h2, PACK_LO(d0.x, d1.x)), ones, A0);
        A1 = FDOT2(__builtin_bit_cast(h2, PACK_HI(d0.x, d1.x)), ones, A1);
        A2 = FDOT2(__builtin_bit_cast(h2, PACK_LO(d0.y, d1.y)), ones, A2);
        A3 = FDOT2(__builtin_bit_cast(h2, PACK_HI(d0.y, d1.y)), ones, A3);
        A0 = FDOT2(__builtin_bit_cast(h2, PACK_LO(d2.x, d3.x)), ones, A0);
        A1 = FDOT2(__builtin_bit_cast(h2, PACK_HI(d2.x, d3.x)), ones, A1);
        A2 = FDOT2(__builtin_bit_cast(h2, PACK_LO(d2.y, d3.y)), ones, A2);
        A3 = FDOT2(__builtin_bit_cast(h2, PACK_HI(d2.y, d3.y)), ones, A3);
    };

    for (int it = 0; it < 4; ++it) {
        int pl = wave + 16 * it;
        int pos = p0 + pl;

        // stage this position's windows (same-wave LDS: in-order, no barrier)
        ivW[lane] = nivw;
        ivB[lane] = nivb;
        int cws = ws_, cwe = we, cbs = bs_, cbe = be;

        // prefetch next position's bounds + windows
        if (it < 3) {
            int npl = pl + 16;
            ws_ = sb[0][npl]; we = sb[0][npl + 1];
            bs_ = sb[1][npl]; be = sb[1][npl + 1];
            nivw = (ws_ + lane < we) ? wf[ws_ + lane] : DUMMY;
            nivb = (bs_ + lane < be) ? bf[bs_ + lane] : DUMMY;
        }

        float wa0 = 0.f, wa1 = 0.f, wa2 = 0.f, wa3 = 0.f;
        float ba0 = 0.f, ba1 = 0.f, ba2 = 0.f, ba3 = 0.f;

        // interleaved white/black chunks: 2 LDS dep-chains in flight
        int ncw = (imin(cwe - cws, 64) + 15) >> 4;
        int ncb = (imin(cbe - cbs, 64) + 15) >> 4;
        int ncm = ncw > ncb ? ncw : ncb;
        for (int c = 0; c < ncm; ++c) {
            if (c < ncw) CHUNK(ivW, c, wa0, wa1, wa2, wa3);
            if (c < ncb) CHUNK(ivB, c, ba0, ba1, ba2, ba3);
        }
        // rare tails (segment > 64 rows)
        for (int tt = cws + 64; tt < cwe; tt += 64) {
            ivW[lane] = (tt + lane < cwe) ? wf[tt + lane] : DUMMY;
            int nc = (imin(cwe - tt, 64) + 15) >> 4;
            for (int c = 0; c < nc; ++c) CHUNK(ivW, c, wa0, wa1, wa2, wa3);
        }
        for (int tt = cbs + 64; tt < cbe; tt += 64) {
            ivB[lane] = (tt + lane < cbe) ? bf[tt + lane] : DUMMY;
            int nc = (imin(cbe - tt, 64) + 15) >> 4;
            for (int c = 0; c < nc; ++c) CHUNK(ivB, c, ba0, ba1, ba2, ba3);
        }

        wa0 += __shfl_xor(wa0, 16); wa0 += __shfl_xor(wa0, 32);
        wa1 += __shfl_xor(wa1, 16); wa1 += __shfl_xor(wa1, 32);
        wa2 += __shfl_xor(wa2, 16); wa2 += __shfl_xor(wa2, 32);
        wa3 += __shfl_xor(wa3, 16); wa3 += __shfl_xor(wa3, 32);
        ba0 += __shfl_xor(ba0, 16); ba0 += __shfl_xor(ba0, 32);
        ba1 += __shfl_xor(ba1, 16); ba1 += __shfl_xor(ba1, 32);
        ba2 += __shfl_xor(ba2, 16); ba2 += __shfl_xor(ba2, 32);
        ba3 += __shfl_xor(ba3, 16); ba3 += __shfl_xor(ba3, 32);

        if (lane < 32) {
            __half2 q0, q1;
            if (g == 0) {
                q0 = __floats2half2_rn(clamp01(wa0 + bb.x), clamp01(wa1 + bb.y));
                q1 = __floats2half2_rn(clamp01(wa2 + bb.z), clamp01(wa3 + bb.w));
            } else {
                q0 = __floats2half2_rn(clamp01(ba0 + bb.x), clamp01(ba1 + bb.y));
                q1 = __floats2half2_rn(clamp01(ba2 + bb.z), clamp01(ba3 + bb.w));
            }
            a1h[g * 32 + k * 2]     = q0;     // white pairs [0..31], black [32..63]
            a1h[g * 32 + k * 2 + 1] = q1;
        }
        // same-wave LDS write->read ordering via lgkmcnt

        const uint4* aq = &a1sq[wave][h * 8];
        float acc = 0.f;
#pragma unroll
        for (int q4 = 0; q4 < 8; ++q4) {
            uint4 qq = aq[q4];
            acc = FDOT2(__builtin_bit_cast(h2, qq.x), w2r[q4 * 4 + 0], acc);
            acc = FDOT2(__builtin_bit_cast(h2, qq.y), w2r[q4 * 4 + 1], acc);
            acc = FDOT2(__builtin_bit_cast(h2, qq.z), w2r[q4 * 4 + 2], acc);
            acc = FDOT2(__builtin_bit_cast(h2, qq.w), w2r[q4 * 4 + 3], acc);
        }
        acc += __shfl_xor(acc, 32);

        float a2v = clamp01(acc + b2j);
        float p = a2v * w3j;
        p += __shfl_xor(p, 16);
        p += __shfl_xor(p, 8);
        p += __shfl_xor(p, 4);
        p += __shfl_xor(p, 2);
        p += __shfl_xor(p, 1);
        if (lane == 0)
            out[pos] = 1.f / (1.f + __expf(-(p + b30)));
    }
}

extern "C" void kernel_launch(void* const* d_in, const int* in_sizes, int n_in,
                              void* d_out, int out_size, void* d_ws, size_t ws_size,
                              hipStream_t stream) {
    const int*   wf = (const int*)d_in[0];
    const int*   wi = (const int*)d_in[1];
    const int*   bf = (const int*)d_in[2];
    const int*   bi = (const int*)d_in[3];
    const float* W1 = (const float*)d_in[4];
    const float* b1 = (const float*)d_in[5];
    const float* W2 = (const float*)d_in[6];
    const float* b2 = (const float*)d_in[7];
    const float* W3 = (const float*)d_in[8];
    const float* b3 = (const float*)d_in[9];
    float* out = (float*)d_out;

    k_all<<<NPOS / 64, 1024, 0, stream>>>(wf, bf, wi, bi, W1, (const float4*)b1,
                                          W2, b2, W3, b3, out);
}

// Round 10
// 24.136 us; speedup vs baseline: 1.1361x; 1.0319x over previous
//
#include <hip/hip_runtime.h>
#include <hip/hip_fp16.h>
#include <math.h>

#define NPOS 16384
#define NTOT 491520
#define NFEAT 768
#define DUMMY 768          // zero row appended to W1T
#define PITCH 68           // halves per W1T row: 136B -> 8B-aligned, bank-friendly

typedef _Float16 h2 __attribute__((ext_vector_type(2)));

__device__ __forceinline__ int imin(int a, int b) { return a < b ? a : b; }
__device__ __forceinline__ float clamp01(float x) { return fminf(fmaxf(x, 0.f), 1.f); }

#if __has_builtin(__builtin_amdgcn_fdot2)
#define FDOT2(a, b, c) __builtin_amdgcn_fdot2((a), (b), (c), false)
#else
#define FDOT2(a, b, c) ((c) + (float)(a)[0] * (float)(b)[0] + (float)(a)[1] * (float)(b)[1])
#endif

// pack (lo16(x), lo16(y)) and (hi16(x), hi16(y)) into uint32s
#if __has_builtin(__builtin_amdgcn_perm)
#define PACK_LO(x, y) __builtin_amdgcn_perm((y), (x), 0x05040100u)
#define PACK_HI(x, y) __builtin_amdgcn_perm((y), (x), 0x07060302u)
#else
#define PACK_LO(x, y) (((x) & 0xFFFFu) | ((y) << 16))
#define PACK_HI(x, y) (((x) >> 16) | ((y) & 0xFFFF0000u))
#endif

__device__ __forceinline__ h2 toh2(__half2 x) { return __builtin_bit_cast(h2, x); }

// ---------------- single fused kernel ----------------
// 256 blocks (1/CU) x 1024 threads (16 waves), ~126KB LDS -> 1 block/CU.
// Phase A (R10): waves 0-13 stage W1 -> LDS, TWO rows per iteration:
//   item (rp, s): lane loads W1[2rp][s*64+lane] and W1[2rp+1][s*64+lane]
//   (256B coalesced each), packs RN -> one ds_write_b32 at dword
//   (s*64+lane)*34 + rp (bank 2*lane+rp -> 2 lanes/bank, free). 28 iters/wave
//   (halved from R9). W2 -> LDS also by these 896 threads (strided tail).
//   Waves 14/15: interpolation search only + dummy zero row -> short pole.
// Phase B (unchanged from R8/R9, passes at 1.953e-3): per position,
//   interleaved white/black 16-row chunks: ds_read_b128 index quad +
//   4 ds_read_b64 rows + 8 v_perm + 8 v_dot2_f32_f16((1,1)) f32 accum;
//   xor-reduce; bias+hardtanh+pack to LDS; head with W2T in VGPRs.
__global__ __launch_bounds__(1024, 4) void k_all(
    const int* __restrict__ wf, const int* __restrict__ bf,
    const int* __restrict__ wi, const int* __restrict__ bi,
    const float* __restrict__ W1, const float4* __restrict__ b1q,
    const float* __restrict__ W2, const float* __restrict__ b2,
    const float* __restrict__ W3, const float* __restrict__ b3,
    float* __restrict__ out)
{
    __shared__ __half  w1t[769 * PITCH];           // 104,584 B
    __shared__ __half2 w2t[2048];                  // [i-pair 0..63][j 0..31]
    __shared__ __align__(16) int ivs[16][2][64];   // per-wave windows (w/b)
    __shared__ uint4   a1sq[16][16];               // per-wave a1 row (128 halfs)
    __shared__ int     sb[2][65];                  // segment boundaries

    int t = threadIdx.x;
    int wave = t >> 6, lane = t & 63;
    int p0 = blockIdx.x * 64;

    // ---- Phase A ----
    if (wave < 14) {
        // 384 pair-items: item = rp*12 + s (rp = row-pair 0..31, s = span 0..11)
#pragma unroll 4
        for (int i = 0; i < 28; ++i) {
            int item = wave + 14 * i;
            if (item >= 384) break;
            int rp = item / 12;                    // wave-uniform -> SALU
            int s = item - rp * 12;
            int c = s * 64 + lane;
            float vlo = W1[(2 * rp) * NFEAT + c];      // 256B coalesced
            float vhi = W1[(2 * rp + 1) * NFEAT + c];  // 256B coalesced
            __half2 pk;
            pk.x = __float2half(vlo);              // RN, numerics = R9
            pk.y = __float2half(vhi);
            *(__half2*)&w1t[c * PITCH + 2 * rp] = pk;  // ds_write_b32, 2 lanes/bank
        }
        // W2 [32][128] f32 -> w2t[i*32+j] = (W2[j][2i], W2[j][2i+1])
        for (int x = t; x < 2048; x += 896) {
            int i = x >> 5, jj = x & 31;
            w2t[x] = __floats2half2_rn(W2[jj * 128 + 2 * i], W2[jj * 128 + 2 * i + 1]);
        }
    } else {
        // Dual interpolation lower_bound per lane (tgt1 = p0+lane, tgt2 = p0+64)
        const int* __restrict__ arr = (wave == 14) ? wi : bi;
        int col = wave - 14;
        int t1 = p0 + lane, t2 = p0 + 64;
        int lo1 = 0, hi1 = 0, g1 = 0;
        int lo2 = 0, hi2 = 0, g2 = 0;
        if (t1 > 0) { hi1 = NTOT; g1 = imin(t1 * 30, NTOT - 1); }
        if (t2 < NPOS) { hi2 = NTOT; g2 = imin(t2 * 30, NTOT - 1); }
        else { lo2 = NTOT; hi2 = NTOT; }
#pragma unroll 1
        for (int it = 0; it < 8; ++it) {
            bool c1 = lo1 < hi1, c2 = lo2 < hi2;
            if (!c1 && !c2) break;
            int v1 = 0, v2 = 0;
            if (c1) v1 = arr[g1];
            if (c2) v2 = arr[g2];
            if (c1) {
                if (v1 < t1) lo1 = g1 + 1; else hi1 = g1;
                int ng = g1 + (t1 - v1) * 30;
                if (ng < lo1 || ng >= hi1) ng = lo1 + ((hi1 - lo1) >> 1);
                g1 = ng;
            }
            if (c2) {
                if (v2 < t2) lo2 = g2 + 1; else hi2 = g2;
                int ng = g2 + (t2 - v2) * 30;
                if (ng < lo2 || ng >= hi2) ng = lo2 + ((hi2 - lo2) >> 1);
                g2 = ng;
            }
        }
#pragma unroll 1
        for (;;) {
            bool c1 = lo1 < hi1, c2 = lo2 < hi2;
            if (!c1 && !c2) break;
            int m1 = 0, m2 = 0, v1 = 0, v2 = 0;
            if (c1) { m1 = lo1 + ((hi1 - lo1) >> 1); v1 = arr[m1]; }
            if (c2) { m2 = lo2 + ((hi2 - lo2) >> 1); v2 = arr[m2]; }
            if (c1) { if (v1 < t1) lo1 = m1 + 1; else hi1 = m1; }
            if (c2) { if (v2 < t2) lo2 = m2 + 1; else hi2 = m2; }
        }
        sb[col][lane] = lo1;
        if (lane == 63) sb[col][64] = lo2;

        int tl = t - 896;
        if (tl < 64) w1t[DUMMY * PITCH + tl] = __float2half(0.f);
    }
    __syncthreads();

    // ---- Phase B ----
    int g = lane >> 4, k = lane & 15;
    int j = lane & 31, h = lane >> 5;

    // first position's bounds + window prefetch (flies during w2r preload)
    int ws_ = sb[0][wave], we = sb[0][wave + 1];
    int bs_ = sb[1][wave], be = sb[1][wave + 1];
    int nivw = (ws_ + lane < we) ? wf[ws_ + lane] : DUMMY;
    int nivb = (bs_ + lane < be) ? bf[bs_ + lane] : DUMMY;

    // W2T slice for this lane's (j,h) into 32 VGPRs
    h2 w2r[32];
#pragma unroll
    for (int i = 0; i < 32; ++i) w2r[i] = toh2(w2t[(h * 32 + i) * 32 + j]);

    float4 bb = b1q[k];
    float b2j = b2[j], w3j = W3[j], b30 = b3[0];

    const h2 ones = {(_Float16)1.0f, (_Float16)1.0f};
    int* ivW = &ivs[wave][0][0];
    int* ivB = &ivs[wave][1][0];
    __half2* a1h = (__half2*)&a1sq[wave][0];

    // chunk: 4 rows (indices miv[c*16+g*4 ..+3]), perm-pair + fdot2, f32 accum
    auto CHUNK = [&](const int* __restrict__ miv, int c,
                     float& A0, float& A1, float& A2, float& A3) {
        uint4 iq = *(const uint4*)&miv[c * 16 + g * 4];
        uint2 d0 = *(const uint2*)&w1t[(int)iq.x * PITCH + k * 4];
        uint2 d1 = *(const uint2*)&w1t[(int)iq.y * PITCH + k * 4];
        uint2 d2 = *(const uint2*)&w1t[(int)iq.z * PITCH + k * 4];
        uint2 d3 = *(const uint2*)&w1t[(int)iq.w * PITCH + k * 4];
        A0 = FDOT2(__builtin_bit_cast(h2, PACK_LO(d0.x, d1.x)), ones, A0);
        A1 = FDOT2(__builtin_bit_cast(h2, PACK_HI(d0.x, d1.x)), ones, A1);
        A2 = FDOT2(__builtin_bit_cast(h2, PACK_LO(d0.y, d1.y)), ones, A2);
        A3 = FDOT2(__builtin_bit_cast(h2, PACK_HI(d0.y, d1.y)), ones, A3);
        A0 = FDOT2(__builtin_bit_cast(h2, PACK_LO(d2.x, d3.x)), ones, A0);
        A1 = FDOT2(__builtin_bit_cast(h2, PACK_HI(d2.x, d3.x)), ones, A1);
        A2 = FDOT2(__builtin_bit_cast(h2, PACK_LO(d2.y, d3.y)), ones, A2);
        A3 = FDOT2(__builtin_bit_cast(h2, PACK_HI(d2.y, d3.y)), ones, A3);
    };

    for (int it = 0; it < 4; ++it) {
        int pl = wave + 16 * it;
        int pos = p0 + pl;

        // stage this position's windows (same-wave LDS: in-order, no barrier)
        ivW[lane] = nivw;
        ivB[lane] = nivb;
        int cws = ws_, cwe = we, cbs = bs_, cbe = be;

        // prefetch next position's bounds + windows
        if (it < 3) {
            int npl = pl + 16;
            ws_ = sb[0][npl]; we = sb[0][npl + 1];
            bs_ = sb[1][npl]; be = sb[1][npl + 1];
            nivw = (ws_ + lane < we) ? wf[ws_ + lane] : DUMMY;
            nivb = (bs_ + lane < be) ? bf[bs_ + lane] : DUMMY;
        }

        float wa0 = 0.f, wa1 = 0.f, wa2 = 0.f, wa3 = 0.f;
        float ba0 = 0.f, ba1 = 0.f, ba2 = 0.f, ba3 = 0.f;

        // interleaved white/black chunks: 2 LDS dep-chains in flight
        int ncw = (imin(cwe - cws, 64) + 15) >> 4;
        int ncb = (imin(cbe - cbs, 64) + 15) >> 4;
        int ncm = ncw > ncb ? ncw : ncb;
        for (int c = 0; c < ncm; ++c) {
            if (c < ncw) CHUNK(ivW, c, wa0, wa1, wa2, wa3);
            if (c < ncb) CHUNK(ivB, c, ba0, ba1, ba2, ba3);
        }
        // rare tails (segment > 64 rows)
        for (int tt = cws + 64; tt < cwe; tt += 64) {
            ivW[lane] = (tt + lane < cwe) ? wf[tt + lane] : DUMMY;
            int nc = (imin(cwe - tt, 64) + 15) >> 4;
            for (int c = 0; c < nc; ++c) CHUNK(ivW, c, wa0, wa1, wa2, wa3);
        }
        for (int tt = cbs + 64; tt < cbe; tt += 64) {
            ivB[lane] = (tt + lane < cbe) ? bf[tt + lane] : DUMMY;
            int nc = (imin(cbe - tt, 64) + 15) >> 4;
            for (int c = 0; c < nc; ++c) CHUNK(ivB, c, ba0, ba1, ba2, ba3);
        }

        wa0 += __shfl_xor(wa0, 16); wa0 += __shfl_xor(wa0, 32);
        wa1 += __shfl_xor(wa1, 16); wa1 += __shfl_xor(wa1, 32);
        wa2 += __shfl_xor(wa2, 16); wa2 += __shfl_xor(wa2, 32);
        wa3 += __shfl_xor(wa3, 16); wa3 += __shfl_xor(wa3, 32);
        ba0 += __shfl_xor(ba0, 16); ba0 += __shfl_xor(ba0, 32);
        ba1 += __shfl_xor(ba1, 16); ba1 += __shfl_xor(ba1, 32);
        ba2 += __shfl_xor(ba2, 16); ba2 += __shfl_xor(ba2, 32);
        ba3 += __shfl_xor(ba3, 16); ba3 += __shfl_xor(ba3, 32);

        if (lane < 32) {
            __half2 q0, q1;
            if (g == 0) {
                q0 = __floats2half2_rn(clamp01(wa0 + bb.x), clamp01(wa1 + bb.y));
                q1 = __floats2half2_rn(clamp01(wa2 + bb.z), clamp01(wa3 + bb.w));
            } else {
                q0 = __floats2half2_rn(clamp01(ba0 + bb.x), clamp01(ba1 + bb.y));
                q1 = __floats2half2_rn(clamp01(ba2 + bb.z), clamp01(ba3 + bb.w));
            }
            a1h[g * 32 + k * 2]     = q0;     // white pairs [0..31], black [32..63]
            a1h[g * 32 + k * 2 + 1] = q1;
        }
        // same-wave LDS write->read ordering via lgkmcnt

        const uint4* aq = &a1sq[wave][h * 8];
        float acc = 0.f;
#pragma unroll
        for (int q4 = 0; q4 < 8; ++q4) {
            uint4 qq = aq[q4];
            acc = FDOT2(__builtin_bit_cast(h2, qq.x), w2r[q4 * 4 + 0], acc);
            acc = FDOT2(__builtin_bit_cast(h2, qq.y), w2r[q4 * 4 + 1], acc);
            acc = FDOT2(__builtin_bit_cast(h2, qq.z), w2r[q4 * 4 + 2], acc);
            acc = FDOT2(__builtin_bit_cast(h2, qq.w), w2r[q4 * 4 + 3], acc);
        }
        acc += __shfl_xor(acc, 32);

        float a2v = clamp01(acc + b2j);
        float p = a2v * w3j;
        p += __shfl_xor(p, 16);
        p += __shfl_xor(p, 8);
        p += __shfl_xor(p, 4);
        p += __shfl_xor(p, 2);
        p += __shfl_xor(p, 1);
        if (lane == 0)
            out[pos] = 1.f / (1.f + __expf(-(p + b30)));
    }
}

extern "C" void kernel_launch(void* const* d_in, const int* in_sizes, int n_in,
                              void* d_out, int out_size, void* d_ws, size_t ws_size,
                              hipStream_t stream) {
    const int*   wf = (const int*)d_in[0];
    const int*   wi = (const int*)d_in[1];
    const int*   bf = (const int*)d_in[2];
    const int*   bi = (const int*)d_in[3];
    const float* W1 = (const float*)d_in[4];
    const float* b1 = (const float*)d_in[5];
    const float* W2 = (const float*)d_in[6];
    const float* b2 = (const float*)d_in[7];
    const float* W3 = (const float*)d_in[8];
    const float* b3 = (const float*)d_in[9];
    float* out = (float*)d_out;

    k_all<<<NPOS / 64, 1024, 0, stream>>>(wf, bf, wi, bi, W1, (const float4*)b1,
                                          W2, b2, W3, b3, out);
}

// Round 11
// 23.946 us; speedup vs baseline: 1.1451x; 1.0080x over previous
//
#include <hip/hip_runtime.h>
#include <hip/hip_fp16.h>
#include <math.h>

#define NPOS 16384
#define NTOT 491520
#define NFEAT 768
#define DUMMY 768          // zero row appended to W1T
#define PITCH 68           // halves per W1T row: 136B -> 8B-aligned, bank-friendly

typedef _Float16 h2 __attribute__((ext_vector_type(2)));

__device__ __forceinline__ int imin(int a, int b) { return a < b ? a : b; }
__device__ __forceinline__ float clamp01(float x) { return fminf(fmaxf(x, 0.f), 1.f); }

#if __has_builtin(__builtin_amdgcn_fdot2)
#define FDOT2(a, b, c) __builtin_amdgcn_fdot2((a), (b), (c), false)
#else
#define FDOT2(a, b, c) ((c) + (float)(a)[0] * (float)(b)[0] + (float)(a)[1] * (float)(b)[1])
#endif

// pack (lo16(x), lo16(y)) and (hi16(x), hi16(y)) into uint32s
#if __has_builtin(__builtin_amdgcn_perm)
#define PACK_LO(x, y) __builtin_amdgcn_perm((y), (x), 0x05040100u)
#define PACK_HI(x, y) __builtin_amdgcn_perm((y), (x), 0x07060302u)
#else
#define PACK_LO(x, y) (((x) & 0xFFFFu) | ((y) << 16))
#define PACK_HI(x, y) (((x) >> 16) | ((y) & 0xFFFF0000u))
#endif

__device__ __forceinline__ h2 toh2(__half2 x) { return __builtin_bit_cast(h2, x); }

// ---------------- single fused kernel ----------------
// 256 blocks (1/CU) x 1024 threads (16 waves), ~126KB LDS -> 1 block/CU.
// Phase A: waves 0-13 stage W1 -> LDS two rows/iter (256B-coalesced reads,
//   packed ds_write_b32, 2 lanes/bank free; exact trip count for unroll).
//   Waves 14/15: interpolation search for segment boundaries + dummy row.
// Phase B (numerics identical to R8-R10, passes at 1.953e-3): per position,
//   interleaved white/black 16-row chunks: ds_read_b128 index quad +
//   4 ds_read_b64 rows + 8 v_perm + 8 v_dot2_f32_f16((1,1)) f32 accum;
//   xor-reduce; bias+hardtanh+pack to LDS; head with W2T in VGPRs (2
//   independent fdot2 chains); results staged in LDS, coalesced 256B store.
__global__ __launch_bounds__(1024, 4) void k_all(
    const int* __restrict__ wf, const int* __restrict__ bf,
    const int* __restrict__ wi, const int* __restrict__ bi,
    const float* __restrict__ W1, const float4* __restrict__ b1q,
    const float* __restrict__ W2, const float* __restrict__ b2,
    const float* __restrict__ W3, const float* __restrict__ b3,
    float* __restrict__ out)
{
    __shared__ __half  w1t[769 * PITCH];           // 104,584 B
    __shared__ __half2 w2t[2048];                  // [i-pair 0..63][j 0..31]
    __shared__ __align__(16) int ivs[16][2][64];   // per-wave windows (w/b)
    __shared__ uint4   a1sq[16][16];               // per-wave a1 row (128 halfs)
    __shared__ int     sb[2][65];                  // segment boundaries
    __shared__ float   outb[64];                   // per-block results

    int t = threadIdx.x;
    int wave = t >> 6, lane = t & 63;
    int p0 = blockIdx.x * 64;

    // ---- Phase A ----
    if (wave < 14) {
        // 384 pair-items: item = rp*12 + s (rp = row-pair 0..31, s = span 0..11)
        int n = (wave <= 5) ? 28 : 27;             // exact trip count: item < 384
#pragma unroll 4
        for (int i = 0; i < n; ++i) {
            int item = wave + 14 * i;
            int rp = item / 12;                    // wave-uniform -> SALU
            int s = item - rp * 12;
            int c = s * 64 + lane;
            float vlo = W1[(2 * rp) * NFEAT + c];      // 256B coalesced
            float vhi = W1[(2 * rp + 1) * NFEAT + c];  // 256B coalesced
            __half2 pk;
            pk.x = __float2half(vlo);              // RN, numerics unchanged
            pk.y = __float2half(vhi);
            *(__half2*)&w1t[c * PITCH + 2 * rp] = pk;  // ds_write_b32, 2 lanes/bank
        }
        // W2 [32][128] f32 -> w2t[i*32+j] = (W2[j][2i], W2[j][2i+1])
        for (int x = t; x < 2048; x += 896) {
            int i = x >> 5, jj = x & 31;
            w2t[x] = __floats2half2_rn(W2[jj * 128 + 2 * i], W2[jj * 128 + 2 * i + 1]);
        }
    } else {
        // Dual interpolation lower_bound per lane (tgt1 = p0+lane, tgt2 = p0+64)
        const int* __restrict__ arr = (wave == 14) ? wi : bi;
        int col = wave - 14;
        int t1 = p0 + lane, t2 = p0 + 64;
        int lo1 = 0, hi1 = 0, g1 = 0;
        int lo2 = 0, hi2 = 0, g2 = 0;
        if (t1 > 0) { hi1 = NTOT; g1 = imin(t1 * 30, NTOT - 1); }
        if (t2 < NPOS) { hi2 = NTOT; g2 = imin(t2 * 30, NTOT - 1); }
        else { lo2 = NTOT; hi2 = NTOT; }
#pragma unroll 1
        for (int it = 0; it < 8; ++it) {
            bool c1 = lo1 < hi1, c2 = lo2 < hi2;
            if (!c1 && !c2) break;
            int v1 = 0, v2 = 0;
            if (c1) v1 = arr[g1];
            if (c2) v2 = arr[g2];
            if (c1) {
                if (v1 < t1) lo1 = g1 + 1; else hi1 = g1;
                int ng = g1 + (t1 - v1) * 30;
                if (ng < lo1 || ng >= hi1) ng = lo1 + ((hi1 - lo1) >> 1);
                g1 = ng;
            }
            if (c2) {
                if (v2 < t2) lo2 = g2 + 1; else hi2 = g2;
                int ng = g2 + (t2 - v2) * 30;
                if (ng < lo2 || ng >= hi2) ng = lo2 + ((hi2 - lo2) >> 1);
                g2 = ng;
            }
        }
#pragma unroll 1
        for (;;) {
            bool c1 = lo1 < hi1, c2 = lo2 < hi2;
            if (!c1 && !c2) break;
            int m1 = 0, m2 = 0, v1 = 0, v2 = 0;
            if (c1) { m1 = lo1 + ((hi1 - lo1) >> 1); v1 = arr[m1]; }
            if (c2) { m2 = lo2 + ((hi2 - lo2) >> 1); v2 = arr[m2]; }
            if (c1) { if (v1 < t1) lo1 = m1 + 1; else hi1 = m1; }
            if (c2) { if (v2 < t2) lo2 = m2 + 1; else hi2 = m2; }
        }
        sb[col][lane] = lo1;
        if (lane == 63) sb[col][64] = lo2;

        int tl = t - 896;
        if (tl < 64) w1t[DUMMY * PITCH + tl] = __float2half(0.f);
    }
    __syncthreads();

    // ---- Phase B ----
    int g = lane >> 4, k = lane & 15;
    int j = lane & 31, h = lane >> 5;

    // first position's bounds + window prefetch (flies during w2r preload)
    int ws_ = sb[0][wave], we = sb[0][wave + 1];
    int bs_ = sb[1][wave], be = sb[1][wave + 1];
    int nivw = (ws_ + lane < we) ? wf[ws_ + lane] : DUMMY;
    int nivb = (bs_ + lane < be) ? bf[bs_ + lane] : DUMMY;

    // W2T slice for this lane's (j,h) into 32 VGPRs
    h2 w2r[32];
#pragma unroll
    for (int i = 0; i < 32; ++i) w2r[i] = toh2(w2t[(h * 32 + i) * 32 + j]);

    float4 bb = b1q[k];
    float b2j = b2[j], w3j = W3[j], b30 = b3[0];

    const h2 ones = {(_Float16)1.0f, (_Float16)1.0f};
    int* ivW = &ivs[wave][0][0];
    int* ivB = &ivs[wave][1][0];
    __half2* a1h = (__half2*)&a1sq[wave][0];

    // chunk: 4 rows (indices miv[c*16+g*4 ..+3]), perm-pair + fdot2, f32 accum
    auto CHUNK = [&](const int* __restrict__ miv, int c,
                     float& A0, float& A1, float& A2, float& A3) {
        uint4 iq = *(const uint4*)&miv[c * 16 + g * 4];
        uint2 d0 = *(const uint2*)&w1t[(int)iq.x * PITCH + k * 4];
        uint2 d1 = *(const uint2*)&w1t[(int)iq.y * PITCH + k * 4];
        uint2 d2 = *(const uint2*)&w1t[(int)iq.z * PITCH + k * 4];
        uint2 d3 = *(const uint2*)&w1t[(int)iq.w * PITCH + k * 4];
        A0 = FDOT2(__builtin_bit_cast(h2, PACK_LO(d0.x, d1.x)), ones, A0);
        A1 = FDOT2(__builtin_bit_cast(h2, PACK_HI(d0.x, d1.x)), ones, A1);
        A2 = FDOT2(__builtin_bit_cast(h2, PACK_LO(d0.y, d1.y)), ones, A2);
        A3 = FDOT2(__builtin_bit_cast(h2, PACK_HI(d0.y, d1.y)), ones, A3);
        A0 = FDOT2(__builtin_bit_cast(h2, PACK_LO(d2.x, d3.x)), ones, A0);
        A1 = FDOT2(__builtin_bit_cast(h2, PACK_HI(d2.x, d3.x)), ones, A1);
        A2 = FDOT2(__builtin_bit_cast(h2, PACK_LO(d2.y, d3.y)), ones, A2);
        A3 = FDOT2(__builtin_bit_cast(h2, PACK_HI(d2.y, d3.y)), ones, A3);
    };

    for (int it = 0; it < 4; ++it) {
        int pl = wave + 16 * it;

        // stage this position's windows (same-wave LDS: in-order, no barrier)
        ivW[lane] = nivw;
        ivB[lane] = nivb;
        int cws = ws_, cwe = we, cbs = bs_, cbe = be;

        // prefetch next position's bounds + windows
        if (it < 3) {
            int npl = pl + 16;
            ws_ = sb[0][npl]; we = sb[0][npl + 1];
            bs_ = sb[1][npl]; be = sb[1][npl + 1];
            nivw = (ws_ + lane < we) ? wf[ws_ + lane] : DUMMY;
            nivb = (bs_ + lane < be) ? bf[bs_ + lane] : DUMMY;
        }

        float wa0 = 0.f, wa1 = 0.f, wa2 = 0.f, wa3 = 0.f;
        float ba0 = 0.f, ba1 = 0.f, ba2 = 0.f, ba3 = 0.f;

        // interleaved white/black chunks: 2 LDS dep-chains in flight
        int ncw = (imin(cwe - cws, 64) + 15) >> 4;
        int ncb = (imin(cbe - cbs, 64) + 15) >> 4;
        int ncm = ncw > ncb ? ncw : ncb;
        for (int c = 0; c < ncm; ++c) {
            if (c < ncw) CHUNK(ivW, c, wa0, wa1, wa2, wa3);
            if (c < ncb) CHUNK(ivB, c, ba0, ba1, ba2, ba3);
        }
        // rare tails (segment > 64 rows)
        for (int tt = cws + 64; tt < cwe; tt += 64) {
            ivW[lane] = (tt + lane < cwe) ? wf[tt + lane] : DUMMY;
            int nc = (imin(cwe - tt, 64) + 15) >> 4;
            for (int c = 0; c < nc; ++c) CHUNK(ivW, c, wa0, wa1, wa2, wa3);
        }
        for (int tt = cbs + 64; tt < cbe; tt += 64) {
            ivB[lane] = (tt + lane < cbe) ? bf[tt + lane] : DUMMY;
            int nc = (imin(cbe - tt, 64) + 15) >> 4;
            for (int c = 0; c < nc; ++c) CHUNK(ivB, c, ba0, ba1, ba2, ba3);
        }

        wa0 += __shfl_xor(wa0, 16); wa0 += __shfl_xor(wa0, 32);
        wa1 += __shfl_xor(wa1, 16); wa1 += __shfl_xor(wa1, 32);
        wa2 += __shfl_xor(wa2, 16); wa2 += __shfl_xor(wa2, 32);
        wa3 += __shfl_xor(wa3, 16); wa3 += __shfl_xor(wa3, 32);
        ba0 += __shfl_xor(ba0, 16); ba0 += __shfl_xor(ba0, 32);
        ba1 += __shfl_xor(ba1, 16); ba1 += __shfl_xor(ba1, 32);
        ba2 += __shfl_xor(ba2, 16); ba2 += __shfl_xor(ba2, 32);
        ba3 += __shfl_xor(ba3, 16); ba3 += __shfl_xor(ba3, 32);

        if (lane < 32) {
            __half2 q0, q1;
            if (g == 0) {
                q0 = __floats2half2_rn(clamp01(wa0 + bb.x), clamp01(wa1 + bb.y));
                q1 = __floats2half2_rn(clamp01(wa2 + bb.z), clamp01(wa3 + bb.w));
            } else {
                q0 = __floats2half2_rn(clamp01(ba0 + bb.x), clamp01(ba1 + bb.y));
                q1 = __floats2half2_rn(clamp01(ba2 + bb.z), clamp01(ba3 + bb.w));
            }
            a1h[g * 32 + k * 2]     = q0;     // white pairs [0..31], black [32..63]
            a1h[g * 32 + k * 2 + 1] = q1;
        }
        // same-wave LDS write->read ordering via lgkmcnt

        // head: two independent fdot2 chains (halves the serial dep depth)
        const uint4* aq = &a1sq[wave][h * 8];
        float acc0 = 0.f, acc1 = 0.f;
#pragma unroll
        for (int q4 = 0; q4 < 8; q4 += 2) {
            uint4 qa = aq[q4];
            uint4 qb = aq[q4 + 1];
            acc0 = FDOT2(__builtin_bit_cast(h2, qa.x), w2r[q4 * 4 + 0], acc0);
            acc1 = FDOT2(__builtin_bit_cast(h2, qb.x), w2r[q4 * 4 + 4], acc1);
            acc0 = FDOT2(__builtin_bit_cast(h2, qa.y), w2r[q4 * 4 + 1], acc0);
            acc1 = FDOT2(__builtin_bit_cast(h2, qb.y), w2r[q4 * 4 + 5], acc1);
            acc0 = FDOT2(__builtin_bit_cast(h2, qa.z), w2r[q4 * 4 + 2], acc0);
            acc1 = FDOT2(__builtin_bit_cast(h2, qb.z), w2r[q4 * 4 + 6], acc1);
            acc0 = FDOT2(__builtin_bit_cast(h2, qa.w), w2r[q4 * 4 + 3], acc0);
            acc1 = FDOT2(__builtin_bit_cast(h2, qb.w), w2r[q4 * 4 + 7], acc1);
        }
        float acc = acc0 + acc1;
        acc += __shfl_xor(acc, 32);

        float a2v = clamp01(acc + b2j);
        float p = a2v * w3j;
        p += __shfl_xor(p, 16);
        p += __shfl_xor(p, 8);
        p += __shfl_xor(p, 4);
        p += __shfl_xor(p, 2);
        p += __shfl_xor(p, 1);
        if (lane == 0)
            outb[pl] = 1.f / (1.f + __expf(-(p + b30)));
    }

    // coalesced 256B output store (one wave) instead of 64 scattered 4B stores
    __syncthreads();
    if (t < 64) out[p0 + t] = outb[t];
}

extern "C" void kernel_launch(void* const* d_in, const int* in_sizes, int n_in,
                              void* d_out, int out_size, void* d_ws, size_t ws_size,
                              hipStream_t stream) {
    const int*   wf = (const int*)d_in[0];
    const int*   wi = (const int*)d_in[1];
    const int*   bf = (const int*)d_in[2];
    const int*   bi = (const int*)d_in[3];
    const float* W1 = (const float*)d_in[4];
    const float* b1 = (const float*)d_in[5];
    const float* W2 = (const float*)d_in[6];
    const float* b2 = (const float*)d_in[7];
    const float* W3 = (const float*)d_in[8];
    const float* b3 = (const float*)d_in[9];
    float* out = (float*)d_out;

    k_all<<<NPOS / 64, 1024, 0, stream>>>(wf, bf, wi, bi, W1, (const float4*)b1,
                                          W2, b2, W3, b3, out);
}